// Round 7
// baseline (1034.582 us; speedup 1.0000x reference)
//
#include <hip/hip_runtime.h>
#include <hip/hip_bf16.h>
#include <stdint.h>

#define DEV __device__ __forceinline__

typedef __attribute__((ext_vector_type(8))) short bf16x8;
typedef __attribute__((ext_vector_type(8))) unsigned short u16x8;
typedef __attribute__((ext_vector_type(4))) unsigned short u16x4;
typedef __attribute__((ext_vector_type(4))) float f32x4;

static constexpr int BB = 4, NN = 8192, DD = 1024, HH = 8, DKK = 128, FFF = 4096;
static constexpr int MM = BB * NN;  // 32768

DEV float bfb2f(unsigned int s) { unsigned int x = s << 16; float f; __builtin_memcpy(&f, &x, 4); return f; }
DEV unsigned short f2bfb(float f) {
    unsigned int x; __builtin_memcpy(&x, &f, 4);
    x += 0x7fffu + ((x >> 16) & 1u);           // RNE
    return (unsigned short)(x >> 16);
}

DEV void gload_lds16(const void* g, void* l) {
    auto gp = (const __attribute__((address_space(1))) void*)(uintptr_t)g;
    auto lp = (__attribute__((address_space(3))) void*)(unsigned int)(uintptr_t)l;
    __builtin_amdgcn_global_load_lds(gp, lp, 16, 0, 0);
}

// ---------------- fp32 -> bf16 pack ----------------
__global__ void k_pack_bf16(const float* __restrict__ in, unsigned short* __restrict__ ob, long n) {
    long i = ((long)blockIdx.x * blockDim.x + threadIdx.x) * 8;
    if (i >= n) return;
    f32x4 a = *(const f32x4*)&in[i];
    f32x4 b = *(const f32x4*)&in[i + 4];
    u16x8 o;
    o[0]=f2bfb(a[0]); o[1]=f2bfb(a[1]); o[2]=f2bfb(a[2]); o[3]=f2bfb(a[3]);
    o[4]=f2bfb(b[0]); o[5]=f2bfb(b[1]); o[6]=f2bfb(b[2]); o[7]=f2bfb(b[3]);
    *(u16x8*)&ob[i] = o;
}

// ---------------- W [R,C] fp32 -> W^T [C,R] bf16 ----------------
__global__ void k_transpose(const float* __restrict__ W, unsigned short* __restrict__ WT, int R, int C) {
    __shared__ float t[32][33];
    const int tid = threadIdx.x;
    const int r0 = blockIdx.y * 32, c0 = blockIdx.x * 32;
    const int lr = tid >> 3, lc = (tid & 7) * 4;
    f32x4 v = *(const f32x4*)&W[(long)(r0 + lr) * C + c0 + lc];
    t[lr][lc + 0] = v[0]; t[lr][lc + 1] = v[1]; t[lr][lc + 2] = v[2]; t[lr][lc + 3] = v[3];
    __syncthreads();
    const int oc = tid >> 3, orr = (tid & 7) * 4;
    u16x4 o;
    o[0] = f2bfb(t[orr + 0][oc]); o[1] = f2bfb(t[orr + 1][oc]);
    o[2] = f2bfb(t[orr + 2][oc]); o[3] = f2bfb(t[orr + 3][oc]);
    *(u16x4*)&WT[(long)(c0 + oc) * R + r0 + orr] = o;
}

// ======================= 256x256 8-phase GEMM, deep-staggered ring =======================
// C[M,N] = A[M,K] @ BT[N,K]^T. BK=64 (ks0,ks1). 8 waves (2M x 4N), 128x64/wave.
// Slots A0..A3,B0..B3 of [256x32] bf16 (16KB), 128 KiB total.
// Even tile reads A0(ph0,1),A1(ph2,3),B0(ph0),B1(ph2); odd tile: A2,A3,B2,B3.
// Stage stream (1 chunk = 2 gloads / phase), DEEP stagger (tile+2 for ks0):
//   even t: ph0 B_{t+1}ks1->B3, ph1 A_{t+1}ks1->A3, ph2 A_{t+2}ks0->A0, ph3 B_{t+2}ks0->B0
//   odd  t: ph0 B_{t+1}ks1->B1, ph1 A_{t+1}ks1->A1, ph2 A_{t+2}ks0->A2, ph3 B_{t+2}ks0->B2
// Steady state 12 loads in flight; vmcnt(8) at ph1,ph3. Invariant: wait at global
// phase g guarantees all stages issued <= g-4 landed (>=4 phases ~ 1300cyc > HBM).
// Verified: ks1 reads (ph2) guarded by wait@ph1 (stages at g-4,g-5); next-tile ks0
// reads (ph0) guarded by wait@prev-ph3 (stages at g-4,g-5). Slot overwrite only
// after last-reader phase's closing barrier. Read-ahead: ph0/ph2 issue 12 ds_reads
// with lgkmcnt(4) (a1f/a3f complete under MFMA); ph1/ph3 issue none.
template <int EPI>
__global__ __launch_bounds__(512, 2)
void k_gemm256(const unsigned short* __restrict__ A, int lda,
               const unsigned short* __restrict__ BT, int ldbt,
               const float* __restrict__ bias0, const float* __restrict__ bias1,
               const float* __restrict__ bias2,
               const unsigned short* __restrict__ resb,
               unsigned short* __restrict__ outp0, unsigned short* __restrict__ outp1,
               unsigned short* __restrict__ outp2,
               float* __restrict__ outf,
               int K, int gridx)
{
    extern __shared__ __align__(128) unsigned short smem[];
    unsigned short* As = smem;              // 4 slots * 8192 shorts
    unsigned short* Bs = smem + 4 * 8192;

    // T1: bijective XCD swizzle (m204)
    const int nwg = gridDim.x;
    int wg = blockIdx.x;
    {
        const int q = nwg >> 3, r = nwg & 7;
        const int xcd = wg & 7, idx = wg >> 3;
        wg = (xcd < r ? xcd * (q + 1) : r * (q + 1) + (xcd - r) * q) + idx;
    }
    const int brow = (wg / gridx) * 256;
    const int bcol = (wg % gridx) * 256;

    const int tid = threadIdx.x;
    const int lane = tid & 63;
    const int w = tid >> 6;
    const int wm = w >> 2, wn = w & 3;
    const int fr = lane & 15;
    const int kg = lane >> 4;

    // staging source (pre-swizzled): dest_lin = tid*16 -> swz -> (row, k)
    const int dl = tid * 16;
    const int soff = dl ^ (((dl >> 7) & 3) << 4);
    const int arow = soff >> 6;
    const int akel = (soff & 63) >> 1;
    const unsigned short* Ab = A + (long)(brow + arow) * lda + akel;
    const unsigned short* Bb = BT + (long)(bcol + arow) * ldbt + akel;

    // precomputed swizzled in-slot BYTE offsets for frag reads
    int aoff[8], boff[4];
    #pragma unroll
    for (int m = 0; m < 8; ++m) { int o = (wm * 128 + m * 16 + fr) * 64 + kg * 16; aoff[m] = o ^ (((o >> 7) & 3) << 4); }
    #pragma unroll
    for (int n = 0; n < 4; ++n) { int o = (wn * 64 + n * 16 + fr) * 64 + kg * 16; boff[n] = o ^ (((o >> 7) & 3) << 4); }

    f32x4 acc[8][4] = {};

#define STG_A(u, ks, slot) do { \
        const unsigned short* _g = Ab + (long)(u) * 64 + (ks) * 32; \
        gload_lds16(_g,              (slot) + tid * 8); \
        gload_lds16(_g + 128L * lda, (slot) + 4096 + tid * 8); } while (0)
#define STG_B(u, ks, slot) do { \
        const unsigned short* _g = Bb + (long)(u) * 64 + (ks) * 32; \
        gload_lds16(_g,               (slot) + tid * 8); \
        gload_lds16(_g + 128L * ldbt, (slot) + 4096 + tid * 8); } while (0)

#define BAR() __builtin_amdgcn_s_barrier()
#define LGKM(N) do { asm volatile("s_waitcnt lgkmcnt(" #N ")" ::: "memory"); \
                     __builtin_amdgcn_sched_barrier(0); } while (0)
#define VM8() asm volatile("s_waitcnt vmcnt(8)" ::: "memory")

#define MFMA16(AF, BF, R0) do { \
        __builtin_amdgcn_s_setprio(1); \
        _Pragma("unroll") \
        for (int m = 0; m < 4; ++m) { \
            _Pragma("unroll") \
            for (int n = 0; n < 4; ++n) \
                acc[(R0) + m][n] = __builtin_amdgcn_mfma_f32_16x16x32_bf16(AF[m], BF[n], acc[(R0) + m][n], 0, 0, 0); \
        } \
        __builtin_amdgcn_s_setprio(0); } while (0)

    // one tile reading slots (sa0,sa1,sb0,sb1); STG0..3 = this tile's 4 stage chunks
#define DO_TILE(sa0, sa1, sb0, sb1, STG0, STG1, STG2, STG3) do { \
        bf16x8 b0f[4], a0f[4], a1f[4], b1f[4], a2f[4], a3f[4]; \
        /* ph0: 12 reads, stage, lgkm(4) */ \
        _Pragma("unroll") \
        for (int n = 0; n < 4; ++n) b0f[n] = *(const bf16x8*)((const char*)(sb0) + boff[n]); \
        _Pragma("unroll") \
        for (int m = 0; m < 4; ++m) a0f[m] = *(const bf16x8*)((const char*)(sa0) + aoff[m]); \
        _Pragma("unroll") \
        for (int m = 0; m < 4; ++m) a1f[m] = *(const bf16x8*)((const char*)(sa0) + aoff[m + 4]); \
        STG0; \
        BAR(); LGKM(4); \
        MFMA16(a0f, b0f, 0); \
        BAR(); \
        /* ph1: no reads, stage, vmcnt(8) */ \
        STG1; VM8(); \
        BAR(); LGKM(0); \
        MFMA16(a1f, b0f, 4); \
        BAR(); \
        /* ph2: 12 reads, stage, lgkm(4) */ \
        _Pragma("unroll") \
        for (int n = 0; n < 4; ++n) b1f[n] = *(const bf16x8*)((const char*)(sb1) + boff[n]); \
        _Pragma("unroll") \
        for (int m = 0; m < 4; ++m) a2f[m] = *(const bf16x8*)((const char*)(sa1) + aoff[m]); \
        _Pragma("unroll") \
        for (int m = 0; m < 4; ++m) a3f[m] = *(const bf16x8*)((const char*)(sa1) + aoff[m + 4]); \
        STG2; \
        BAR(); LGKM(4); \
        MFMA16(a2f, b1f, 0); \
        BAR(); \
        /* ph3: no reads, stage, vmcnt(8) */ \
        STG3; VM8(); \
        BAR(); LGKM(0); \
        MFMA16(a3f, b1f, 4); \
        BAR(); \
    } while (0)

    unsigned short* A0 = As;            unsigned short* A1 = As + 8192;
    unsigned short* A2 = As + 16384;    unsigned short* A3 = As + 24576;
    unsigned short* B0 = Bs;            unsigned short* B1 = Bs + 8192;
    unsigned short* B2 = Bs + 16384;    unsigned short* B3 = Bs + 24576;

    const int NT = K >> 6;              // even for all our shapes (16 or 64)
    // prologue: 6 chunks in ledger order, then retire the first 2 (tile0 ks0)
    STG_A(0, 0, A0); STG_B(0, 0, B0);
    STG_B(0, 1, B1); STG_A(0, 1, A1);
    STG_A(1, 0, A2); STG_B(1, 0, B2);
    VM8();
    BAR();

    for (int t = 0; t < NT; t += 2) {
        const int u1 = t + 1;
        const int u2 = (t + 2 < NT) ? t + 2 : 0;
        const int u3 = (t + 3 < NT) ? t + 3 : 0;
        DO_TILE(A0, A1, B0, B1,
                STG_B(u1, 1, B3), STG_A(u1, 1, A3), STG_A(u2, 0, A0), STG_B(u2, 0, B0));
        DO_TILE(A2, A3, B2, B3,
                STG_B(u2, 1, B1), STG_A(u2, 1, A1), STG_A(u3, 0, A2), STG_B(u3, 0, B2));
    }
    asm volatile("s_waitcnt vmcnt(0)" ::: "memory");   // drain before block exit
#undef DO_TILE
#undef MFMA16
#undef VM8
#undef LGKM
#undef BAR
#undef STG_A
#undef STG_B

    // epilogue; C/D: col = lane&15, row = (lane>>4)*4 + j
    const int q4 = (lane >> 4) * 4;
    if constexpr (EPI == 1) {
        const int mat = bcol >> 10;
        const float* bp = mat == 0 ? bias0 : (mat == 1 ? bias1 : bias2);
        unsigned short* op = mat == 0 ? outp0 : (mat == 1 ? outp1 : outp2);
        const int dc0 = bcol & 1023;
        #pragma unroll
        for (int m = 0; m < 8; ++m)
            #pragma unroll
            for (int n = 0; n < 4; ++n) {
                const int c = dc0 + wn * 64 + n * 16 + fr;
                const float bv = bp[c];
                const int hh = c >> 7, dk = c & 127;
                #pragma unroll
                for (int j = 0; j < 4; ++j) {
                    const int r = brow + wm * 128 + m * 16 + q4 + j;
                    const long idx = (((long)(r >> 13) * 8 + hh) * 8192 + (r & 8191)) * 128 + dk;
                    op[idx] = f2bfb(acc[m][n][j] + bv);
                }
            }
    } else if constexpr (EPI == 2) {
        #pragma unroll
        for (int m = 0; m < 8; ++m)
            #pragma unroll
            for (int n = 0; n < 4; ++n) {
                const int c = bcol + wn * 64 + n * 16 + fr;
                const float bv = bias0[c];
                #pragma unroll
                for (int j = 0; j < 4; ++j) {
                    const int r = brow + wm * 128 + m * 16 + q4 + j;
                    float v = acc[m][n][j] + bv;
                    v = v / (1.f + __expf(-v));
                    outp0[(long)r * FFF + c] = f2bfb(v);
                }
            }
    } else {
        #pragma unroll
        for (int m = 0; m < 8; ++m)
            #pragma unroll
            for (int n = 0; n < 4; ++n) {
                const int c = bcol + wn * 64 + n * 16 + fr;
                const float bv = bias0[c];
                #pragma unroll
                for (int j = 0; j < 4; ++j) {
                    const int r = brow + wm * 128 + m * 16 + q4 + j;
                    float v = acc[m][n][j] + bv + bfb2f(resb[(long)r * DD + c]);
                    outf[(long)r * DD + c] = v;
                }
            }
    }
}

// ---------------- 128x128 GEMM (attn: EPI 3) ----------------
template <int EPI>
__global__ __launch_bounds__(256, 2)
void k_gemm(const unsigned short* __restrict__ A, int lda, long sAz,
            const unsigned short* __restrict__ BT, int ldbt, long sBz,
            const float* __restrict__ bias,
            const float* __restrict__ resf,
            const unsigned short* __restrict__ resb,
            unsigned short* __restrict__ outp,
            float* __restrict__ outf,
            int K)
{
    __shared__ __align__(16) unsigned short As[128 * 32];
    __shared__ __align__(16) unsigned short Bs[128 * 32];
    const int tid = threadIdx.x;
    const int z = blockIdx.z;
    A  += (long)z * sAz;
    BT += (long)z * sBz;
    const int brow = blockIdx.y * 128;
    const int bcol = blockIdx.x * 128;

    const int c0 = tid, c1 = tid + 256;
    const unsigned short* Ap0 = A + (long)(brow + (c0 >> 2)) * lda + (c0 & 3) * 8;
    const unsigned short* Ap1 = A + (long)(brow + (c1 >> 2)) * lda + (c1 & 3) * 8;
    const unsigned short* Bp0 = BT + (long)(bcol + (c0 >> 2)) * ldbt + (c0 & 3) * 8;
    const unsigned short* Bp1 = BT + (long)(bcol + (c1 >> 2)) * ldbt + (c1 & 3) * 8;
    unsigned short* AsD0 = &As[c0 * 8];
    unsigned short* AsD1 = &As[c1 * 8];
    unsigned short* BsD0 = &Bs[c0 * 8];
    unsigned short* BsD1 = &Bs[c1 * 8];

    const int lane = tid & 63;
    const int w = tid >> 6;
    const int wr = (w >> 1) * 64;
    const int wc = (w & 1) * 64;
    const int fr = lane & 15;
    const int fk = (lane >> 4) * 8;

    f32x4 acc[4][4] = {};

    for (int kt = 0; kt < K; kt += 32) {
        gload_lds16(Ap0 + kt, AsD0);
        gload_lds16(Ap1 + kt, AsD1);
        gload_lds16(Bp0 + kt, BsD0);
        gload_lds16(Bp1 + kt, BsD1);
        __syncthreads();
        bf16x8 af[4], bfr[4];
        #pragma unroll
        for (int m = 0; m < 4; ++m) af[m] = *(const bf16x8*)&As[(wr + m * 16 + fr) * 32 + fk];
        #pragma unroll
        for (int n = 0; n < 4; ++n) bfr[n] = *(const bf16x8*)&Bs[(wc + n * 16 + fr) * 32 + fk];
        #pragma unroll
        for (int m = 0; m < 4; ++m)
            #pragma unroll
            for (int n = 0; n < 4; ++n)
                acc[m][n] = __builtin_amdgcn_mfma_f32_16x16x32_bf16(af[m], bfr[n], acc[m][n], 0, 0, 0);
        __syncthreads();
    }

    const int orow = (lane >> 4) * 4;
    #pragma unroll
    for (int m = 0; m < 4; ++m) {
        #pragma unroll
        for (int n = 0; n < 4; ++n) {
            const int d = bcol + wc + n * 16 + fr;
            #pragma unroll
            for (int j = 0; j < 4; ++j) {
                const int r = brow + wr + m * 16 + orow + j;
                float v = acc[m][n][j];
                if constexpr (EPI == 3) {
                    long xi = ((long)(z >> 3) * NN + r) * DD + (z & 7) * DKK + d;
                    v += resf[xi];
                    outp[xi] = f2bfb(v);
                }
            }
        }
    }
    (void)bias; (void)resb; (void)outf;
}

// ---------------- in-place per-head LN on K and V (+delta on K) ----------------
__global__ void k_ln(unsigned short* __restrict__ Kb, unsigned short* __restrict__ Vb,
                     const float* __restrict__ gk, const float* __restrict__ bek,
                     const float* __restrict__ dx)
{
    const int tid = threadIdx.x;
    const int lane = tid & 63;
    const long row = (long)blockIdx.x * 4 + (tid >> 6);
    unsigned short* buf = blockIdx.y ? Vb : Kb;
    const int h = (int)((row >> 13) & 7);
    const int n = (int)(row & 8191);
    unsigned int* p = (unsigned int*)(buf + row * 128) + lane;
    const unsigned int u = *p;
    float f0 = bfb2f(u & 0xffffu);
    float f1 = bfb2f(u >> 16);
    float s = f0 + f1, q = f0 * f0 + f1 * f1;
    #pragma unroll
    for (int o = 32; o; o >>= 1) { s += __shfl_xor(s, o); q += __shfl_xor(q, o); }
    const float mean = s * (1.f / 128.f);
    const float var  = q * (1.f / 128.f) - mean * mean;
    const float rstd = rsqrtf(var + 1e-5f);
    const int gi = h * 128 + lane * 2;
    float o0 = (f0 - mean) * rstd * gk[gi]     + bek[gi];
    float o1 = (f1 - mean) * rstd * gk[gi + 1] + bek[gi + 1];
    if (blockIdx.y == 0) { const float dl = dx[n]; o0 *= dl; o1 *= dl; }
    *p = (unsigned int)f2bfb(o0) | ((unsigned int)f2bfb(o1) << 16);
}

// ---------------- scores partials ----------------
__global__ __launch_bounds__(256, 2)
void k_scorespart(const unsigned short* __restrict__ Kb, const unsigned short* __restrict__ Vb,
                  float* __restrict__ part)
{
    __shared__ __align__(16) unsigned short KT[128 * 136];
    __shared__ __align__(16) unsigned short VT[128 * 136];
    const int tid = threadIdx.x;
    const int bh = blockIdx.y, split = blockIdx.x;
    const unsigned short* Kp = Kb + (long)bh * NN * DKK;
    const unsigned short* Vp = Vb + (long)bh * NN * DKK;
    const int lane = tid & 63, w = tid >> 6;
    const int wr = (w >> 1) * 64, wc = (w & 1) * 64, fr = lane & 15, fk = (lane >> 4) * 8;
    const int nrow = tid >> 1, dblk = (tid & 1) * 64;
    f32x4 acc[4][4] = {};
    for (int c = 0; c < 8; ++c) {
        const int n0 = (split * 8 + c) * 128;
        bf16x8 kv[8], vv[8];
        #pragma unroll
        for (int i = 0; i < 8; ++i) {
            kv[i] = *(const bf16x8*)&Kp[(long)(n0 + nrow) * DKK + dblk + i * 8];
            vv[i] = *(const bf16x8*)&Vp[(long)(n0 + nrow) * DKK + dblk + i * 8];
        }
        __syncthreads();
        #pragma unroll
        for (int i = 0; i < 8; ++i)
            #pragma unroll
            for (int j = 0; j < 8; ++j) {
                const int dd = dblk + i * 8 + j;
                KT[dd * 136 + nrow] = (unsigned short)kv[i][j];
                VT[dd * 136 + nrow] = (unsigned short)vv[i][j];
            }
        __syncthreads();
        #pragma unroll
        for (int ks = 0; ks < 4; ++ks) {
            bf16x8 af[4], bfr[4];
            #pragma unroll
            for (int m = 0; m < 4; ++m) af[m] = *(const bf16x8*)&KT[(wr + m * 16 + fr) * 136 + ks * 32 + fk];
            #pragma unroll
            for (int n = 0; n < 4; ++n) bfr[n] = *(const bf16x8*)&VT[(wc + n * 16 + fr) * 136 + ks * 32 + fk];
            #pragma unroll
            for (int m = 0; m < 4; ++m)
                #pragma unroll
                for (int n = 0; n < 4; ++n)
                    acc[m][n] = __builtin_amdgcn_mfma_f32_16x16x32_bf16(af[m], bfr[n], acc[m][n], 0, 0, 0);
        }
    }
    float* P = part + (long)(bh * 8 + split) * 16384;
    const int orow = (lane >> 4) * 4;
    #pragma unroll
    for (int m = 0; m < 4; ++m)
        #pragma unroll
        for (int n = 0; n < 4; ++n)
            #pragma unroll
            for (int j = 0; j < 4; ++j) {
                const int dD = wr + m * 16 + orow + j;
                const int e  = wc + n * 16 + fr;
                P[dD * 128 + e] = acc[m][n][j];
            }
}

__global__ void k_scoresred(const float* __restrict__ part, unsigned short* __restrict__ scT)
{
    const int bh = blockIdx.x, tid = threadIdx.x;
    const float* P = part + (long)bh * 8 * 16384;
    for (int i = tid; i < 16384; i += 256) {
        float s = 0.f;
        #pragma unroll
        for (int sp = 0; sp < 8; ++sp) s += P[sp * 16384 + i];
        const int d = i >> 7, e = i & 127;
        scT[(long)bh * 16384 + e * 128 + d] = f2bfb(s * (1.f / 8192.f));
    }
}

extern "C" void kernel_launch(void* const* d_in, const int* in_sizes, int n_in,
                              void* d_out, int out_size, void* d_ws, size_t ws_size,
                              hipStream_t stream)
{
    const float* x   = (const float*)d_in[0];
    const float* dx  = (const float*)d_in[1];
    const float* Wq  = (const float*)d_in[2];
    const float* bq  = (const float*)d_in[3];
    const float* Wk  = (const float*)d_in[4];
    const float* bk  = (const float*)d_in[5];
    const float* Wv  = (const float*)d_in[6];
    const float* bv  = (const float*)d_in[7];
    const float* gk  = (const float*)d_in[8];
    const float* bek = (const float*)d_in[9];
    const float* W1  = (const float*)d_in[10];
    const float* b1  = (const float*)d_in[11];
    const float* W2  = (const float*)d_in[12];
    const float* b2  = (const float*)d_in[13];
    float* out = (float*)d_out;
    (void)in_sizes; (void)n_in; (void)out_size; (void)ws_size;

    hipFuncSetAttribute((const void*)k_gemm256<1>, hipFuncAttributeMaxDynamicSharedMemorySize, 131072);
    hipFuncSetAttribute((const void*)k_gemm256<2>, hipFuncAttributeMaxDynamicSharedMemorySize, 131072);
    hipFuncSetAttribute((const void*)k_gemm256<3>, hipFuncAttributeMaxDynamicSharedMemorySize, 131072);

    char* ws = (char*)d_ws;
    size_t off = 0;
    auto alloc = [&](size_t bytes) { void* p = ws + off; off += (bytes + 255) & ~(size_t)255; return p; };
    unsigned short* WqkvT = (unsigned short*)alloc((size_t)3 * DD * DD * 2);  // [3072][1024]
    unsigned short* W1T   = (unsigned short*)alloc((size_t)FFF * DD * 2);     // [4096][1024]
    unsigned short* W2T   = (unsigned short*)alloc((size_t)DD * FFF * 2);     // [1024][4096]
    unsigned short* scT   = (unsigned short*)alloc((size_t)32 * 16384 * 2);
    unsigned short* xb    = (unsigned short*)alloc((size_t)MM * DD * 2);      // dead after QKV
    unsigned short* Kb    = (unsigned short*)alloc((size_t)MM * DD * 2);      // dead after scores
    unsigned short* Vb    = (unsigned short*)alloc((size_t)MM * DD * 2);      // dead after scores
    unsigned short* x1b   = (unsigned short*)alloc((size_t)MM * DD * 2);
    unsigned short* hb    = xb;                        // h: 16384x4096 bf16 == xb+Kb region
    float* part           = (float*)x1b;               // 16.8MB, dead before x1 written
    unsigned short* Qb    = (unsigned short*)out;      // d_out as Q scratch

    // 1. pack x -> bf16; transpose weights
    k_pack_bf16<<<dim3(((long)MM * DD) / 8 / 256), 256, 0, stream>>>(x, xb, (long)MM * DD);
    k_transpose<<<dim3(DD / 32, DD / 32), 256, 0, stream>>>(Wq, WqkvT, DD, DD);
    k_transpose<<<dim3(DD / 32, DD / 32), 256, 0, stream>>>(Wk, WqkvT + (size_t)DD * DD, DD, DD);
    k_transpose<<<dim3(DD / 32, DD / 32), 256, 0, stream>>>(Wv, WqkvT + (size_t)2 * DD * DD, DD, DD);
    k_transpose<<<dim3(FFF / 32, DD / 32), 256, 0, stream>>>(W1, W1T, DD, FFF);
    k_transpose<<<dim3(DD / 32, FFF / 32), 256, 0, stream>>>(W2, W2T, FFF, DD);

    // 2. fused QKV: [32768,1024] @ [3072,1024]^T -> head-layout Q/K/V
    k_gemm256<1><<<dim3((MM / 256) * (3072 / 256)), 512, 131072, stream>>>(
        xb, DD, WqkvT, DD, bq, bk, bv, nullptr, Qb, Kb, Vb, nullptr, DD, 3072 / 256);

    // 3. per-head LN on K and V, delta on K
    k_ln<<<dim3((BB * HH * NN) / 4, 2), 256, 0, stream>>>(Kb, Vb, gk, bek, dx);

    // 4. scores = K^T V / N
    k_scorespart<<<dim3(8, 32), 256, 0, stream>>>(Kb, Vb, part);
    k_scoresred<<<dim3(32), 256, 0, stream>>>(part, scT);

    // 5. x1 = x + Q @ scores (batched over b,h)
    k_gemm<3><<<dim3(1, NN / 128, BB * HH), 256, 0, stream>>>(Qb, DKK, (long)NN * DKK, scT, DKK, 16384L,
                                                              nullptr, x, nullptr, x1b, nullptr, DKK);

    // 6. FFN in 2 row-chunks of 16384: out = x1 + W2(silu(W1 x1 + b1)) + b2  [f32]
    for (int c = 0; c < 2; ++c) {
        const unsigned short* xc = x1b + (size_t)c * 16384 * DD;
        k_gemm256<2><<<dim3((16384 / 256) * (FFF / 256)), 512, 131072, stream>>>(
            xc, DD, W1T, DD, b1, nullptr, nullptr, nullptr, hb, nullptr, nullptr, nullptr, DD, FFF / 256);
        k_gemm256<3><<<dim3((16384 / 256) * (DD / 256)), 512, 131072, stream>>>(
            hb, FFF, W2T, FFF, b2, nullptr, nullptr, xc, nullptr, nullptr, nullptr,
            out + (size_t)c * 16384 * DD, FFF, DD / 256);
    }
}

// Round 8
// 1000.341 us; speedup vs baseline: 1.0342x; 1.0342x over previous
//
#include <hip/hip_runtime.h>
#include <hip/hip_bf16.h>
#include <stdint.h>

#define DEV __device__ __forceinline__

typedef __attribute__((ext_vector_type(8))) short bf16x8;
typedef __attribute__((ext_vector_type(8))) unsigned short u16x8;
typedef __attribute__((ext_vector_type(4))) unsigned short u16x4;
typedef __attribute__((ext_vector_type(4))) float f32x4;

static constexpr int BB = 4, NN = 8192, DD = 1024, HH = 8, DKK = 128, FFF = 4096;
static constexpr int MM = BB * NN;  // 32768

DEV float bfb2f(unsigned int s) { unsigned int x = s << 16; float f; __builtin_memcpy(&f, &x, 4); return f; }
DEV unsigned short f2bfb(float f) {
    unsigned int x; __builtin_memcpy(&x, &f, 4);
    x += 0x7fffu + ((x >> 16) & 1u);           // RNE
    return (unsigned short)(x >> 16);
}

DEV void gload_lds16(const void* g, void* l) {
    auto gp = (const __attribute__((address_space(1))) void*)(uintptr_t)g;
    auto lp = (__attribute__((address_space(3))) void*)(unsigned int)(uintptr_t)l;
    __builtin_amdgcn_global_load_lds(gp, lp, 16, 0, 0);
}

// ---------------- fp32 -> bf16 pack ----------------
__global__ void k_pack_bf16(const float* __restrict__ in, unsigned short* __restrict__ ob, long n) {
    long i = ((long)blockIdx.x * blockDim.x + threadIdx.x) * 8;
    if (i >= n) return;
    f32x4 a = *(const f32x4*)&in[i];
    f32x4 b = *(const f32x4*)&in[i + 4];
    u16x8 o;
    o[0]=f2bfb(a[0]); o[1]=f2bfb(a[1]); o[2]=f2bfb(a[2]); o[3]=f2bfb(a[3]);
    o[4]=f2bfb(b[0]); o[5]=f2bfb(b[1]); o[6]=f2bfb(b[2]); o[7]=f2bfb(b[3]);
    *(u16x8*)&ob[i] = o;
}

// ---------------- W [R,C] fp32 -> W^T [C,R] bf16 ----------------
__global__ void k_transpose(const float* __restrict__ W, unsigned short* __restrict__ WT, int R, int C) {
    __shared__ float t[32][33];
    const int tid = threadIdx.x;
    const int r0 = blockIdx.y * 32, c0 = blockIdx.x * 32;
    const int lr = tid >> 3, lc = (tid & 7) * 4;
    f32x4 v = *(const f32x4*)&W[(long)(r0 + lr) * C + c0 + lc];
    t[lr][lc + 0] = v[0]; t[lr][lc + 1] = v[1]; t[lr][lc + 2] = v[2]; t[lr][lc + 3] = v[3];
    __syncthreads();
    const int oc = tid >> 3, orr = (tid & 7) * 4;
    u16x4 o;
    o[0] = f2bfb(t[orr + 0][oc]); o[1] = f2bfb(t[orr + 1][oc]);
    o[2] = f2bfb(t[orr + 2][oc]); o[3] = f2bfb(t[orr + 3][oc]);
    *(u16x4*)&WT[(long)(c0 + oc) * R + r0 + orr] = o;
}

// ============ 256x256 8-phase GEMM, persistent blocks + periodic ring ============
// Grid = 256 blocks; block b handles tiles swz(b) + p*256, p in [0,npass).
// Ring as R7 (slots A0..3,B0..3 of [256x32], deep stagger, vmcnt(8)@ph1,3).
// PERIODIC ledger: the last two tiles' wrap-stages load the NEXT OUTPUT TILE's
// K-tiles 0,1 into the canonical prologue slots -> next pass starts with the
// invariant already satisfied: no drain, no refill; epilogue overlaps staging.
template <int EPI>
__global__ __launch_bounds__(512, 2)
void k_gemm256(const unsigned short* __restrict__ A, int lda,
               const unsigned short* __restrict__ BT, int ldbt,
               const float* __restrict__ bias0, const float* __restrict__ bias1,
               const float* __restrict__ bias2,
               const unsigned short* __restrict__ resb,
               unsigned short* __restrict__ outp0, unsigned short* __restrict__ outp1,
               unsigned short* __restrict__ outp2,
               float* __restrict__ outf,
               int K, int gridx, int npass)
{
    extern __shared__ __align__(128) unsigned short smem[];
    unsigned short* As = smem;              // 4 slots * 8192 shorts
    unsigned short* Bs = smem + 4 * 8192;

    // XCD-chunked bijection on [0,256): xcd = b&7 owns 32 consecutive tiles
    const int wg0 = (blockIdx.x & 7) * 32 + (blockIdx.x >> 3);

    const int tid = threadIdx.x;
    const int lane = tid & 63;
    const int w = tid >> 6;
    const int wm = w >> 2, wn = w & 3;      // 8 waves: 2M x 4N
    const int fr = lane & 15;
    const int kg = lane >> 4;

    // staging source (pre-swizzled): dest_lin = tid*16 -> swz -> (row, k)
    const int dl = tid * 16;
    const int soff = dl ^ (((dl >> 7) & 3) << 4);
    const int arow = soff >> 6;
    const int akel = (soff & 63) >> 1;

    // swizzled in-slot BYTE offsets for frag reads
    int aoff[8], boff[4];
    #pragma unroll
    for (int m = 0; m < 8; ++m) { int o = (wm * 128 + m * 16 + fr) * 64 + kg * 16; aoff[m] = o ^ (((o >> 7) & 3) << 4); }
    #pragma unroll
    for (int n = 0; n < 4; ++n) { int o = (wn * 64 + n * 16 + fr) * 64 + kg * 16; boff[n] = o ^ (((o >> 7) & 3) << 4); }

#define STG_A(base, u, ks, slot) do { \
        const unsigned short* _g = (base) + (long)(u) * 64 + (ks) * 32; \
        gload_lds16(_g,              (slot) + tid * 8); \
        gload_lds16(_g + 128L * lda, (slot) + 4096 + tid * 8); } while (0)
#define STG_B(base, u, ks, slot) do { \
        const unsigned short* _g = (base) + (long)(u) * 64 + (ks) * 32; \
        gload_lds16(_g,               (slot) + tid * 8); \
        gload_lds16(_g + 128L * ldbt, (slot) + 4096 + tid * 8); } while (0)

#define BAR() __builtin_amdgcn_s_barrier()
#define LGKM(N) do { asm volatile("s_waitcnt lgkmcnt(" #N ")" ::: "memory"); \
                     __builtin_amdgcn_sched_barrier(0); } while (0)
#define VM8() asm volatile("s_waitcnt vmcnt(8)" ::: "memory")

#define MFMA16(AF, BF, R0) do { \
        __builtin_amdgcn_s_setprio(1); \
        _Pragma("unroll") \
        for (int m = 0; m < 4; ++m) { \
            _Pragma("unroll") \
            for (int n = 0; n < 4; ++n) \
                acc[(R0) + m][n] = __builtin_amdgcn_mfma_f32_16x16x32_bf16(AF[m], BF[n], acc[(R0) + m][n], 0, 0, 0); \
        } \
        __builtin_amdgcn_s_setprio(0); } while (0)

#define DO_TILE(sa0, sa1, sb0, sb1, STG0, STG1, STG2, STG3) do { \
        bf16x8 b0f[4], a0f[4], a1f[4], b1f[4], a2f[4], a3f[4]; \
        _Pragma("unroll") \
        for (int n = 0; n < 4; ++n) b0f[n] = *(const bf16x8*)((const char*)(sb0) + boff[n]); \
        _Pragma("unroll") \
        for (int m = 0; m < 4; ++m) a0f[m] = *(const bf16x8*)((const char*)(sa0) + aoff[m]); \
        _Pragma("unroll") \
        for (int m = 0; m < 4; ++m) a1f[m] = *(const bf16x8*)((const char*)(sa0) + aoff[m + 4]); \
        STG0; \
        BAR(); LGKM(4); \
        MFMA16(a0f, b0f, 0); \
        BAR(); \
        STG1; VM8(); \
        BAR(); LGKM(0); \
        MFMA16(a1f, b0f, 4); \
        BAR(); \
        _Pragma("unroll") \
        for (int n = 0; n < 4; ++n) b1f[n] = *(const bf16x8*)((const char*)(sb1) + boff[n]); \
        _Pragma("unroll") \
        for (int m = 0; m < 4; ++m) a2f[m] = *(const bf16x8*)((const char*)(sa1) + aoff[m]); \
        _Pragma("unroll") \
        for (int m = 0; m < 4; ++m) a3f[m] = *(const bf16x8*)((const char*)(sa1) + aoff[m + 4]); \
        STG2; \
        BAR(); LGKM(4); \
        MFMA16(a2f, b1f, 0); \
        BAR(); \
        STG3; VM8(); \
        BAR(); LGKM(0); \
        MFMA16(a3f, b1f, 4); \
        BAR(); \
    } while (0)

    unsigned short* A0 = As;            unsigned short* A1 = As + 8192;
    unsigned short* A2 = As + 16384;    unsigned short* A3 = As + 24576;
    unsigned short* B0 = Bs;            unsigned short* B1 = Bs + 8192;
    unsigned short* B2 = Bs + 16384;    unsigned short* B3 = Bs + 24576;

    const int NT = K >> 6;              // even, >= 4

    // pass-0 pointers + prologue (6 chunks, ledger order) — done ONCE
    int wg = wg0;
    int brow = (wg / gridx) * 256;
    int bcol = (wg % gridx) * 256;
    const unsigned short* Ab = A + (long)(brow + arow) * lda + akel;
    const unsigned short* Bb = BT + (long)(bcol + arow) * ldbt + akel;
    STG_A(Ab, 0, 0, A0); STG_B(Bb, 0, 0, B0);
    STG_B(Bb, 0, 1, B1); STG_A(Ab, 0, 1, A1);
    STG_A(Ab, 1, 0, A2); STG_B(Bb, 1, 0, B2);
    VM8();
    BAR();

    for (int p = 0; p < npass; ++p) {
        // next output tile (last pass: harmless re-point at tile wg0)
        const int wgN = (p + 1 < npass) ? (wg0 + (p + 1) * 256) : wg0;
        const int browN = (wgN / gridx) * 256;
        const int bcolN = (wgN % gridx) * 256;
        const unsigned short* Ab2 = A + (long)(browN + arow) * lda + akel;
        const unsigned short* Bb2 = BT + (long)(bcolN + arow) * ldbt + akel;

        f32x4 acc[8][4] = {};

        for (int t = 0; t + 2 < NT; t += 2) {
            DO_TILE(A0, A1, B0, B1,
                    STG_B(Bb, t + 1, 1, B3), STG_A(Ab, t + 1, 1, A3),
                    STG_A(Ab, t + 2, 0, A0), STG_B(Bb, t + 2, 0, B0));
            DO_TILE(A2, A3, B2, B3,
                    STG_B(Bb, t + 2, 1, B1), STG_A(Ab, t + 2, 1, A1),
                    STG_A(Ab, t + 3, 0, A2), STG_B(Bb, t + 3, 0, B2));
        }
        // peeled final pair: wrap-stages target NEXT output tile's K-tiles 0,1
        DO_TILE(A0, A1, B0, B1,
                STG_B(Bb, NT - 1, 1, B3), STG_A(Ab, NT - 1, 1, A3),
                STG_A(Ab2, 0, 0, A0), STG_B(Bb2, 0, 0, B0));
        DO_TILE(A2, A3, B2, B3,
                STG_B(Bb2, 0, 1, B1), STG_A(Ab2, 0, 1, A1),
                STG_A(Ab2, 1, 0, A2), STG_B(Bb2, 1, 0, B2));

        // epilogue (registers only; overlaps in-flight staging of next tile)
        const int q4 = (lane >> 4) * 4;
        if constexpr (EPI == 1) {
            const int mat = bcol >> 10;
            const float* bp = mat == 0 ? bias0 : (mat == 1 ? bias1 : bias2);
            unsigned short* op = mat == 0 ? outp0 : (mat == 1 ? outp1 : outp2);
            const int dc0 = bcol & 1023;
            #pragma unroll
            for (int m = 0; m < 8; ++m)
                #pragma unroll
                for (int n = 0; n < 4; ++n) {
                    const int c = dc0 + wn * 64 + n * 16 + fr;
                    const float bv = bp[c];
                    const int hh = c >> 7, dk = c & 127;
                    #pragma unroll
                    for (int j = 0; j < 4; ++j) {
                        const int r = brow + wm * 128 + m * 16 + q4 + j;
                        const long idx = (((long)(r >> 13) * 8 + hh) * 8192 + (r & 8191)) * 128 + dk;
                        op[idx] = f2bfb(acc[m][n][j] + bv);
                    }
                }
        } else if constexpr (EPI == 2) {
            #pragma unroll
            for (int m = 0; m < 8; ++m)
                #pragma unroll
                for (int n = 0; n < 4; ++n) {
                    const int c = bcol + wn * 64 + n * 16 + fr;
                    const float bv = bias0[c];
                    #pragma unroll
                    for (int j = 0; j < 4; ++j) {
                        const int r = brow + wm * 128 + m * 16 + q4 + j;
                        float v = acc[m][n][j] + bv;
                        v = v / (1.f + __expf(-v));
                        outp0[(long)r * FFF + c] = f2bfb(v);
                    }
                }
        } else {
            #pragma unroll
            for (int m = 0; m < 8; ++m)
                #pragma unroll
                for (int n = 0; n < 4; ++n) {
                    const int c = bcol + wn * 64 + n * 16 + fr;
                    const float bv = bias0[c];
                    #pragma unroll
                    for (int j = 0; j < 4; ++j) {
                        const int r = brow + wm * 128 + m * 16 + q4 + j;
                        float v = acc[m][n][j] + bv + bfb2f(resb[(long)r * DD + c]);
                        outf[(long)r * DD + c] = v;
                    }
                }
        }

        brow = browN; bcol = bcolN; Ab = Ab2; Bb = Bb2;
    }
    asm volatile("s_waitcnt vmcnt(0)" ::: "memory");   // drain before block exit
#undef DO_TILE
#undef MFMA16
#undef VM8
#undef LGKM
#undef BAR
#undef STG_A
#undef STG_B
}

// ---------------- 128x128 GEMM (attn: EPI 3) ----------------
template <int EPI>
__global__ __launch_bounds__(256, 2)
void k_gemm(const unsigned short* __restrict__ A, int lda, long sAz,
            const unsigned short* __restrict__ BT, int ldbt, long sBz,
            const float* __restrict__ bias,
            const float* __restrict__ resf,
            const unsigned short* __restrict__ resb,
            unsigned short* __restrict__ outp,
            float* __restrict__ outf,
            int K)
{
    __shared__ __align__(16) unsigned short As[128 * 32];
    __shared__ __align__(16) unsigned short Bs[128 * 32];
    const int tid = threadIdx.x;
    const int z = blockIdx.z;
    A  += (long)z * sAz;
    BT += (long)z * sBz;
    const int brow = blockIdx.y * 128;
    const int bcol = blockIdx.x * 128;

    const int c0 = tid, c1 = tid + 256;
    const unsigned short* Ap0 = A + (long)(brow + (c0 >> 2)) * lda + (c0 & 3) * 8;
    const unsigned short* Ap1 = A + (long)(brow + (c1 >> 2)) * lda + (c1 & 3) * 8;
    const unsigned short* Bp0 = BT + (long)(bcol + (c0 >> 2)) * ldbt + (c0 & 3) * 8;
    const unsigned short* Bp1 = BT + (long)(bcol + (c1 >> 2)) * ldbt + (c1 & 3) * 8;
    unsigned short* AsD0 = &As[c0 * 8];
    unsigned short* AsD1 = &As[c1 * 8];
    unsigned short* BsD0 = &Bs[c0 * 8];
    unsigned short* BsD1 = &Bs[c1 * 8];

    const int lane = tid & 63;
    const int w = tid >> 6;
    const int wr = (w >> 1) * 64;
    const int wc = (w & 1) * 64;
    const int fr = lane & 15;
    const int fk = (lane >> 4) * 8;

    f32x4 acc[4][4] = {};

    for (int kt = 0; kt < K; kt += 32) {
        gload_lds16(Ap0 + kt, AsD0);
        gload_lds16(Ap1 + kt, AsD1);
        gload_lds16(Bp0 + kt, BsD0);
        gload_lds16(Bp1 + kt, BsD1);
        __syncthreads();
        bf16x8 af[4], bfr[4];
        #pragma unroll
        for (int m = 0; m < 4; ++m) af[m] = *(const bf16x8*)&As[(wr + m * 16 + fr) * 32 + fk];
        #pragma unroll
        for (int n = 0; n < 4; ++n) bfr[n] = *(const bf16x8*)&Bs[(wc + n * 16 + fr) * 32 + fk];
        #pragma unroll
        for (int m = 0; m < 4; ++m)
            #pragma unroll
            for (int n = 0; n < 4; ++n)
                acc[m][n] = __builtin_amdgcn_mfma_f32_16x16x32_bf16(af[m], bfr[n], acc[m][n], 0, 0, 0);
        __syncthreads();
    }

    const int orow = (lane >> 4) * 4;
    #pragma unroll
    for (int m = 0; m < 4; ++m) {
        #pragma unroll
        for (int n = 0; n < 4; ++n) {
            const int d = bcol + wc + n * 16 + fr;
            #pragma unroll
            for (int j = 0; j < 4; ++j) {
                const int r = brow + wr + m * 16 + orow + j;
                float v = acc[m][n][j];
                if constexpr (EPI == 3) {
                    long xi = ((long)(z >> 3) * NN + r) * DD + (z & 7) * DKK + d;
                    v += resf[xi];
                    outp[xi] = f2bfb(v);
                }
            }
        }
    }
    (void)bias; (void)resb; (void)outf;
}

// ---------------- in-place per-head LN on K and V (+delta on K) ----------------
__global__ void k_ln(unsigned short* __restrict__ Kb, unsigned short* __restrict__ Vb,
                     const float* __restrict__ gk, const float* __restrict__ bek,
                     const float* __restrict__ dx)
{
    const int tid = threadIdx.x;
    const int lane = tid & 63;
    const long row = (long)blockIdx.x * 4 + (tid >> 6);
    unsigned short* buf = blockIdx.y ? Vb : Kb;
    const int h = (int)((row >> 13) & 7);
    const int n = (int)(row & 8191);
    unsigned int* p = (unsigned int*)(buf + row * 128) + lane;
    const unsigned int u = *p;
    float f0 = bfb2f(u & 0xffffu);
    float f1 = bfb2f(u >> 16);
    float s = f0 + f1, q = f0 * f0 + f1 * f1;
    #pragma unroll
    for (int o = 32; o; o >>= 1) { s += __shfl_xor(s, o); q += __shfl_xor(q, o); }
    const float mean = s * (1.f / 128.f);
    const float var  = q * (1.f / 128.f) - mean * mean;
    const float rstd = rsqrtf(var + 1e-5f);
    const int gi = h * 128 + lane * 2;
    float o0 = (f0 - mean) * rstd * gk[gi]     + bek[gi];
    float o1 = (f1 - mean) * rstd * gk[gi + 1] + bek[gi + 1];
    if (blockIdx.y == 0) { const float dl = dx[n]; o0 *= dl; o1 *= dl; }
    *p = (unsigned int)f2bfb(o0) | ((unsigned int)f2bfb(o1) << 16);
}

// ---------------- scores partials ----------------
__global__ __launch_bounds__(256, 2)
void k_scorespart(const unsigned short* __restrict__ Kb, const unsigned short* __restrict__ Vb,
                  float* __restrict__ part)
{
    __shared__ __align__(16) unsigned short KT[128 * 136];
    __shared__ __align__(16) unsigned short VT[128 * 136];
    const int tid = threadIdx.x;
    const int bh = blockIdx.y, split = blockIdx.x;
    const unsigned short* Kp = Kb + (long)bh * NN * DKK;
    const unsigned short* Vp = Vb + (long)bh * NN * DKK;
    const int lane = tid & 63, w = tid >> 6;
    const int wr = (w >> 1) * 64, wc = (w & 1) * 64, fr = lane & 15, fk = (lane >> 4) * 8;
    const int nrow = tid >> 1, dblk = (tid & 1) * 64;
    f32x4 acc[4][4] = {};
    for (int c = 0; c < 8; ++c) {
        const int n0 = (split * 8 + c) * 128;
        bf16x8 kv[8], vv[8];
        #pragma unroll
        for (int i = 0; i < 8; ++i) {
            kv[i] = *(const bf16x8*)&Kp[(long)(n0 + nrow) * DKK + dblk + i * 8];
            vv[i] = *(const bf16x8*)&Vp[(long)(n0 + nrow) * DKK + dblk + i * 8];
        }
        __syncthreads();
        #pragma unroll
        for (int i = 0; i < 8; ++i)
            #pragma unroll
            for (int j = 0; j < 8; ++j) {
                const int dd = dblk + i * 8 + j;
                KT[dd * 136 + nrow] = (unsigned short)kv[i][j];
                VT[dd * 136 + nrow] = (unsigned short)vv[i][j];
            }
        __syncthreads();
        #pragma unroll
        for (int ks = 0; ks < 4; ++ks) {
            bf16x8 af[4], bfr[4];
            #pragma unroll
            for (int m = 0; m < 4; ++m) af[m] = *(const bf16x8*)&KT[(wr + m * 16 + fr) * 136 + ks * 32 + fk];
            #pragma unroll
            for (int n = 0; n < 4; ++n) bfr[n] = *(const bf16x8*)&VT[(wc + n * 16 + fr) * 136 + ks * 32 + fk];
            #pragma unroll
            for (int m = 0; m < 4; ++m)
                #pragma unroll
                for (int n = 0; n < 4; ++n)
                    acc[m][n] = __builtin_amdgcn_mfma_f32_16x16x32_bf16(af[m], bfr[n], acc[m][n], 0, 0, 0);
        }
    }
    float* P = part + (long)(bh * 8 + split) * 16384;
    const int orow = (lane >> 4) * 4;
    #pragma unroll
    for (int m = 0; m < 4; ++m)
        #pragma unroll
        for (int n = 0; n < 4; ++n)
            #pragma unroll
            for (int j = 0; j < 4; ++j) {
                const int dD = wr + m * 16 + orow + j;
                const int e  = wc + n * 16 + fr;
                P[dD * 128 + e] = acc[m][n][j];
            }
}

__global__ void k_scoresred(const float* __restrict__ part, unsigned short* __restrict__ scT)
{
    const int bh = blockIdx.x, tid = threadIdx.x;
    const float* P = part + (long)bh * 8 * 16384;
    for (int i = tid; i < 16384; i += 256) {
        float s = 0.f;
        #pragma unroll
        for (int sp = 0; sp < 8; ++sp) s += P[sp * 16384 + i];
        const int d = i >> 7, e = i & 127;
        scT[(long)bh * 16384 + e * 128 + d] = f2bfb(s * (1.f / 8192.f));
    }
}

extern "C" void kernel_launch(void* const* d_in, const int* in_sizes, int n_in,
                              void* d_out, int out_size, void* d_ws, size_t ws_size,
                              hipStream_t stream)
{
    const float* x   = (const float*)d_in[0];
    const float* dx  = (const float*)d_in[1];
    const float* Wq  = (const float*)d_in[2];
    const float* bq  = (const float*)d_in[3];
    const float* Wk  = (const float*)d_in[4];
    const float* bk  = (const float*)d_in[5];
    const float* Wv  = (const float*)d_in[6];
    const float* bv  = (const float*)d_in[7];
    const float* gk  = (const float*)d_in[8];
    const float* bek = (const float*)d_in[9];
    const float* W1  = (const float*)d_in[10];
    const float* b1  = (const float*)d_in[11];
    const float* W2  = (const float*)d_in[12];
    const float* b2  = (const float*)d_in[13];
    float* out = (float*)d_out;
    (void)in_sizes; (void)n_in; (void)out_size; (void)ws_size;

    hipFuncSetAttribute((const void*)k_gemm256<1>, hipFuncAttributeMaxDynamicSharedMemorySize, 131072);
    hipFuncSetAttribute((const void*)k_gemm256<2>, hipFuncAttributeMaxDynamicSharedMemorySize, 131072);
    hipFuncSetAttribute((const void*)k_gemm256<3>, hipFuncAttributeMaxDynamicSharedMemorySize, 131072);

    char* ws = (char*)d_ws;
    size_t off = 0;
    auto alloc = [&](size_t bytes) { void* p = ws + off; off += (bytes + 255) & ~(size_t)255; return p; };
    unsigned short* WqkvT = (unsigned short*)alloc((size_t)3 * DD * DD * 2);  // [3072][1024]
    unsigned short* W1T   = (unsigned short*)alloc((size_t)FFF * DD * 2);     // [4096][1024]
    unsigned short* W2T   = (unsigned short*)alloc((size_t)DD * FFF * 2);     // [1024][4096]
    unsigned short* scT   = (unsigned short*)alloc((size_t)32 * 16384 * 2);
    unsigned short* xb    = (unsigned short*)alloc((size_t)MM * DD * 2);      // dead after QKV
    unsigned short* Kb    = (unsigned short*)alloc((size_t)MM * DD * 2);      // dead after scores
    unsigned short* Vb    = (unsigned short*)alloc((size_t)MM * DD * 2);      // dead after scores
    unsigned short* x1b   = (unsigned short*)alloc((size_t)MM * DD * 2);
    unsigned short* hb    = xb;                        // h: 16384x4096 bf16 == xb+Kb region
    float* part           = (float*)x1b;               // 16.8MB, dead before x1 written
    unsigned short* Qb    = (unsigned short*)out;      // d_out as Q scratch

    // 1. pack x -> bf16; transpose weights
    k_pack_bf16<<<dim3(((long)MM * DD) / 8 / 256), 256, 0, stream>>>(x, xb, (long)MM * DD);
    k_transpose<<<dim3(DD / 32, DD / 32), 256, 0, stream>>>(Wq, WqkvT, DD, DD);
    k_transpose<<<dim3(DD / 32, DD / 32), 256, 0, stream>>>(Wk, WqkvT + (size_t)DD * DD, DD, DD);
    k_transpose<<<dim3(DD / 32, DD / 32), 256, 0, stream>>>(Wv, WqkvT + (size_t)2 * DD * DD, DD, DD);
    k_transpose<<<dim3(FFF / 32, DD / 32), 256, 0, stream>>>(W1, W1T, DD, FFF);
    k_transpose<<<dim3(DD / 32, FFF / 32), 256, 0, stream>>>(W2, W2T, FFF, DD);

    // 2. fused QKV: tiles = 128x12 = 1536 -> npass 6
    k_gemm256<1><<<dim3(256), 512, 131072, stream>>>(
        xb, DD, WqkvT, DD, bq, bk, bv, nullptr, Qb, Kb, Vb, nullptr, DD, 3072 / 256, 6);

    // 3. per-head LN on K and V, delta on K
    k_ln<<<dim3((BB * HH * NN) / 4, 2), 256, 0, stream>>>(Kb, Vb, gk, bek, dx);

    // 4. scores = K^T V / N
    k_scorespart<<<dim3(8, 32), 256, 0, stream>>>(Kb, Vb, part);
    k_scoresred<<<dim3(32), 256, 0, stream>>>(part, scT);

    // 5. x1 = x + Q @ scores (batched over b,h)
    k_gemm<3><<<dim3(1, NN / 128, BB * HH), 256, 0, stream>>>(Qb, DKK, (long)NN * DKK, scT, DKK, 16384L,
                                                              nullptr, x, nullptr, x1b, nullptr, DKK);

    // 6. FFN in 2 row-chunks of 16384
    for (int c = 0; c < 2; ++c) {
        const unsigned short* xc = x1b + (size_t)c * 16384 * DD;
        // FFN1: tiles = 64x16 = 1024 -> npass 4
        k_gemm256<2><<<dim3(256), 512, 131072, stream>>>(
            xc, DD, W1T, DD, b1, nullptr, nullptr, nullptr, hb, nullptr, nullptr, nullptr, DD, FFF / 256, 4);
        // FFN2: tiles = 64x4 = 256 -> npass 1
        k_gemm256<3><<<dim3(256), 512, 131072, stream>>>(
            hb, FFF, W2T, FFF, b2, nullptr, nullptr, xc, nullptr, nullptr, nullptr,
            out + (size_t)c * 16384 * DD, FFF, DD / 256, 1);
    }
}